// Round 5
// baseline (36.880 us; speedup 1.0000x reference)
//
#include <hip/hip_runtime.h>
#include <math.h>

#define NB 4
#define WDIM 128
#define KDIM 256
#define EDIM 256

__device__ __forceinline__ float dot4(float4 a, float4 b) {
    return a.x * b.x + a.y * b.y + a.z * b.z + a.w * b.w;
}

// ---------------- k_ut5: dual GEMM u,t ----------------
// grid 512: blk = b*128 + kt*4 + eq. Block = 8 k's x 64 e's. thread: e = eq*64+(tid&63), ks = tid>>6 (2 k's).
__global__ __launch_bounds__(256) void k_ut5(const float* __restrict__ x,
                                             const float* __restrict__ lin_w,
                                             const float* __restrict__ lin_b,
                                             float* __restrict__ u_ws,
                                             float* __restrict__ t_ws) {
    __shared__ float vrow[8 * WDIM];   // [k 8][w 128]
    const int blk = blockIdx.x;
    const int b  = blk >> 7;
    const int kt = (blk >> 2) & 31;
    const int eq = blk & 3;
    const int k0 = kt * 8;
    const int tid = threadIdx.x;
    const int e  = eq * 64 + (tid & 63);
    const int ks = tid >> 6;

    if (tid < WDIM) {
        const float* xp = x + ((size_t)b * WDIM + tid) * KDIM + k0;
        float4 v0 = *(const float4*)xp;
        float4 v1 = *(const float4*)(xp + 4);
        vrow[0 * WDIM + tid] = v0.x; vrow[1 * WDIM + tid] = v0.y;
        vrow[2 * WDIM + tid] = v0.z; vrow[3 * WDIM + tid] = v0.w;
        vrow[4 * WDIM + tid] = v1.x; vrow[5 * WDIM + tid] = v1.y;
        vrow[6 * WDIM + tid] = v1.z; vrow[7 * WDIM + tid] = v1.w;
    }
    __syncthreads();

    const float4* wr = (const float4*)(lin_w + (size_t)e * 2 * WDIM);
    float u0 = 0.f, u1 = 0.f, t0 = 0.f, t1 = 0.f;
#pragma unroll 8
    for (int q = 0; q < 32; ++q) {
        float4 w1 = wr[q];
        float4 w2 = wr[32 + q];
        float4 va = *(const float4*)&vrow[(ks * 2 + 0) * WDIM + q * 4];
        float4 vb = *(const float4*)&vrow[(ks * 2 + 1) * WDIM + q * 4];
        u0 += dot4(w1, va); u1 += dot4(w1, vb);
        t0 += dot4(w2, va); t1 += dot4(w2, vb);
    }
    const float lb = lin_b[e];
    const int k = k0 + ks * 2;
    const size_t o0 = ((size_t)b * KDIM + k) * EDIM + e;
    u_ws[o0] = u0;         u_ws[o0 + EDIM] = u1;
    t_ws[o0] = t0 + lb;    t_ws[o0 + EDIM] = t1 + lb;
}

// ---------------- k_e5: e[b,i,j] = sum_e a2|u_i+t_j| + 1.5(ru_i+rt_j) + bias ----------------
// grid 1024: blk = b*256 + it*8 + jt. Block = 8i x 32j; wave wv = i-pair; lane: s=lane&7, jj=lane>>3.
// e-index per lane: e = q*32 + s*4  (8 consecutive s-lanes cover 128 contiguous bytes per row).
__global__ __launch_bounds__(256, 4) void k_e5(const float* __restrict__ a_vec,
                                               const float* __restrict__ bias,
                                               const float* __restrict__ u_ws,
                                               const float* __restrict__ t_ws,
                                               float* __restrict__ e_ws) {
    __shared__ float a2_lds[EDIM];
    const int blk = blockIdx.x;
    const int b  = blk >> 8;
    const int it = (blk >> 3) & 31;
    const int jt = blk & 7;
    const int i0 = it * 8;
    const int j0 = jt * 32;
    const int tid  = threadIdx.x;
    const int wv   = tid >> 6;
    const int lane = tid & 63;
    const int s  = lane & 7;
    const int jj = lane >> 3;
    const int iA = i0 + wv * 2;

    if (tid < 64) {
        float4 av = *(const float4*)(a_vec + tid * 4);
        *(float4*)&a2_lds[tid * 4] =
            make_float4(0.4f * av.x, 0.4f * av.y, 0.4f * av.z, 0.4f * av.w);
    }

    // u rows for this wave's i-pair, in registers (layout e = q*32 + s*4)
    const float* uAp = u_ws + ((size_t)b * KDIM + iA) * EDIM;
    float4 uA[8], uB[8];
#pragma unroll
    for (int q = 0; q < 8; ++q) {
        uA[q] = *(const float4*)(uAp + q * 32 + s * 4);
        uB[q] = *(const float4*)(uAp + EDIM + q * 32 + s * 4);
    }
    __syncthreads();

    // per-lane ru partials
    float ruA = 0.f, ruB = 0.f;
#pragma unroll
    for (int q = 0; q < 8; ++q) {
        float4 a2 = *(const float4*)&a2_lds[q * 32 + s * 4];
        ruA += dot4(a2, uA[q]);
        ruB += dot4(a2, uB[q]);
    }

    const float* tb = t_ws + (size_t)b * KDIM * EDIM;
#pragma unroll
    for (int jg = 0; jg < 4; ++jg) {
        const int j = j0 + jg * 8 + jj;
        const float* tr = tb + (size_t)j * EDIM;
        float4 tld[8];
#pragma unroll
        for (int q = 0; q < 8; ++q) tld[q] = *(const float4*)(tr + q * 32 + s * 4);

        float accA = 0.f, accB = 0.f, rt = 0.f;
#pragma unroll
        for (int q = 0; q < 8; ++q) {
            float4 a2 = *(const float4*)&a2_lds[q * 32 + s * 4];
            float4 t4 = tld[q];
            rt += dot4(a2, t4);
            accA += a2.x * fabsf(uA[q].x + t4.x) + a2.y * fabsf(uA[q].y + t4.y)
                  + a2.z * fabsf(uA[q].z + t4.z) + a2.w * fabsf(uA[q].w + t4.w);
            accB += a2.x * fabsf(uB[q].x + t4.x) + a2.y * fabsf(uB[q].y + t4.y)
                  + a2.z * fabsf(uB[q].z + t4.z) + a2.w * fabsf(uB[q].w + t4.w);
        }
        float zA = accA + 1.5f * (ruA + rt);
        float zB = accB + 1.5f * (ruB + rt);
        zA += __shfl_xor(zA, 1, 64); zB += __shfl_xor(zB, 1, 64);
        zA += __shfl_xor(zA, 2, 64); zB += __shfl_xor(zB, 2, 64);
        zA += __shfl_xor(zA, 4, 64); zB += __shfl_xor(zB, 4, 64);
        if (s == 0) {
            e_ws[((size_t)b * KDIM + iA) * KDIM + j]     = zA + bias[(size_t)iA * KDIM + j];
            e_ws[((size_t)b * KDIM + iA + 1) * KDIM + j] = zB + bias[(size_t)(iA + 1) * KDIM + j];
        }
    }
}

// ---------------- k_sh5: softmax + h = sigmoid(attn @ v), transposed write ----------------
// grid 1024: blk = b*256 + it*4 + wq. Block = 4 i's x 32 w's (w-quarter).
__global__ __launch_bounds__(256) void k_sh5(const float* __restrict__ x,
                                             const float* __restrict__ e_ws,
                                             float* __restrict__ out) {
    __shared__ float attn_lds[4][260];
    const int blk = blockIdx.x;
    const int b  = blk >> 8;
    const int it = (blk >> 2) & 63;
    const int wq = blk & 3;
    const int i0 = it * 4;
    const int w0 = wq * 32;
    const int tid  = threadIdx.x;
    const int wv   = tid >> 6;
    const int lane = tid & 63;

    // softmax of row i0+wv (wave-parallel, contiguous 1 KB read)
    {
        float4 ev = *(const float4*)(e_ws + ((size_t)b * KDIM + i0 + wv) * KDIM + lane * 4);
        float m = fmaxf(fmaxf(ev.x, ev.y), fmaxf(ev.z, ev.w));
#pragma unroll
        for (int o = 1; o < 64; o <<= 1) m = fmaxf(m, __shfl_xor(m, o, 64));
        float4 p;
        p.x = __expf(ev.x - m); p.y = __expf(ev.y - m);
        p.z = __expf(ev.z - m); p.w = __expf(ev.w - m);
        float ssum = p.x + p.y + p.z + p.w;
#pragma unroll
        for (int o = 1; o < 64; o <<= 1) ssum += __shfl_xor(ssum, o, 64);
        const float inv = 1.0f / ssum;
        p.x *= inv; p.y *= inv; p.z *= inv; p.w *= inv;
        *(float4*)&attn_lds[wv][lane * 4] = p;
    }
    __syncthreads();

    // h-phase: wave wv -> w-oct; lane: s = lane&7 (j-slices), ww = lane>>3
    const int s  = lane & 7;
    const int ww = lane >> 3;
    const int w  = w0 + wv * 8 + ww;
    const float* xr = x + ((size_t)b * WDIM + w) * KDIM;
    float acc[4] = {0.f, 0.f, 0.f, 0.f};
#pragma unroll
    for (int q = 0; q < 8; ++q) {
        float4 x4 = *(const float4*)(xr + q * 32 + s * 4);
#pragma unroll
        for (int i = 0; i < 4; ++i) {
            float4 at = *(const float4*)&attn_lds[i][q * 32 + s * 4];
            acc[i] += dot4(at, x4);
        }
    }
#pragma unroll
    for (int i = 0; i < 4; ++i) {
        acc[i] += __shfl_xor(acc[i], 1, 64);
        acc[i] += __shfl_xor(acc[i], 2, 64);
        acc[i] += __shfl_xor(acc[i], 4, 64);
    }
    if (s == 0) {
        float4 o;
        o.x = 1.f / (1.f + __expf(-acc[0]));
        o.y = 1.f / (1.f + __expf(-acc[1]));
        o.z = 1.f / (1.f + __expf(-acc[2]));
        o.w = 1.f / (1.f + __expf(-acc[3]));
        *(float4*)(out + ((size_t)b * WDIM + w) * KDIM + i0) = o;
    }
}

extern "C" void kernel_launch(void* const* d_in, const int* in_sizes, int n_in,
                              void* d_out, int out_size, void* d_ws, size_t ws_size,
                              hipStream_t stream) {
    (void)in_sizes; (void)n_in; (void)out_size; (void)ws_size;
    const float* x     = (const float*)d_in[0];
    const float* lin_w = (const float*)d_in[1];
    const float* lin_b = (const float*)d_in[2];
    const float* a_vec = (const float*)d_in[3];
    const float* bias  = (const float*)d_in[4];
    float* out = (float*)d_out;

    float* u_ws = (float*)d_ws;                      // 262144 f
    float* t_ws = u_ws + (size_t)NB * KDIM * EDIM;   // 262144 f
    float* e_ws = t_ws + (size_t)NB * KDIM * EDIM;   // 262144 f

    k_ut5<<<512, 256, 0, stream>>>(x, lin_w, lin_b, u_ws, t_ws);
    k_e5<<<1024, 256, 0, stream>>>(a_vec, bias, u_ws, t_ws, e_ws);
    k_sh5<<<1024, 256, 0, stream>>>(x, e_ws, out);
}

// Round 6
// 35.924 us; speedup vs baseline: 1.0266x; 1.0266x over previous
//
#include <hip/hip_runtime.h>
#include <math.h>

#define NB 4
#define WDIM 128
#define KDIM 256
#define EDIM 256

__device__ __forceinline__ float dot4(float4 a, float4 b) {
    return a.x * b.x + a.y * b.y + a.z * b.z + a.w * b.w;
}

// ---------------- k_ut6: dual GEMM u,t (round-5 structure) ----------------
// grid 512: blk = b*128 + kt*4 + eq. Block = 8 k's x 64 e's.
__global__ __launch_bounds__(256) void k_ut6(const float* __restrict__ x,
                                             const float* __restrict__ lin_w,
                                             const float* __restrict__ lin_b,
                                             float* __restrict__ u_ws,
                                             float* __restrict__ t_ws) {
    __shared__ float vrow[8 * WDIM];   // [k 8][w 128]
    const int blk = blockIdx.x;
    const int b  = blk >> 7;
    const int kt = (blk >> 2) & 31;
    const int eq = blk & 3;
    const int k0 = kt * 8;
    const int tid = threadIdx.x;
    const int e  = eq * 64 + (tid & 63);
    const int ks = tid >> 6;

    if (tid < WDIM) {
        const float* xp = x + ((size_t)b * WDIM + tid) * KDIM + k0;
        float4 v0 = *(const float4*)xp;
        float4 v1 = *(const float4*)(xp + 4);
        vrow[0 * WDIM + tid] = v0.x; vrow[1 * WDIM + tid] = v0.y;
        vrow[2 * WDIM + tid] = v0.z; vrow[3 * WDIM + tid] = v0.w;
        vrow[4 * WDIM + tid] = v1.x; vrow[5 * WDIM + tid] = v1.y;
        vrow[6 * WDIM + tid] = v1.z; vrow[7 * WDIM + tid] = v1.w;
    }
    __syncthreads();

    const float4* wr = (const float4*)(lin_w + (size_t)e * 2 * WDIM);
    float u0 = 0.f, u1 = 0.f, t0 = 0.f, t1 = 0.f;
#pragma unroll 8
    for (int q = 0; q < 32; ++q) {
        float4 w1 = wr[q];
        float4 w2 = wr[32 + q];
        float4 va = *(const float4*)&vrow[(ks * 2 + 0) * WDIM + q * 4];
        float4 vb = *(const float4*)&vrow[(ks * 2 + 1) * WDIM + q * 4];
        u0 += dot4(w1, va); u1 += dot4(w1, vb);
        t0 += dot4(w2, va); t1 += dot4(w2, vb);
    }
    const float lb = lin_b[e];
    const int k = k0 + ks * 2;
    const size_t o0 = ((size_t)b * KDIM + k) * EDIM + e;
    u_ws[o0] = u0;         u_ws[o0 + EDIM] = u1;
    t_ws[o0] = t0 + lb;    t_ws[o0 + EDIM] = t1 + lb;
}

// ---------------- k_e6: e[b,i,j] = sum_e a2|u_i+t_j| + 1.5(ru_i+rt_j) + bias ----------------
// grid 1024: blk = b*256 + it*8 + jt. Block = 8i x 32j.
// wave wv owns j in [j0+wv*8, j0+wv*8+8); lane = (s = lane&7 e-slice, jj = lane>>3 -> its j).
// u staged in LDS (shared by all waves, broadcast reads). t row per lane in regs. a2 in regs.
__global__ __launch_bounds__(256) void k_e6(const float* __restrict__ a_vec,
                                            const float* __restrict__ bias,
                                            const float* __restrict__ u_ws,
                                            const float* __restrict__ t_ws,
                                            float* __restrict__ e_ws) {
    __shared__ float u_lds[8 * 256];
    __shared__ float ru_lds[8];
    const int blk = blockIdx.x;
    const int b  = blk >> 8;
    const int it = (blk >> 3) & 31;
    const int jt = blk & 7;
    const int i0 = it * 8;
    const int j0 = jt * 32;
    const int tid  = threadIdx.x;
    const int wv   = tid >> 6;
    const int lane = tid & 63;
    const int s  = lane & 7;
    const int jj = lane >> 3;
    const int j  = j0 + wv * 8 + jj;

    // issue t-row loads first (latency overlaps staging)
    const float* tr = t_ws + ((size_t)b * KDIM + j) * EDIM;
    float4 tld[8];
#pragma unroll
    for (int q = 0; q < 8; ++q) tld[q] = *(const float4*)(tr + q * 32 + s * 4);

    // a2 = 0.4*a in regs
    float4 a2[8];
#pragma unroll
    for (int q = 0; q < 8; ++q) {
        float4 av = *(const float4*)(a_vec + q * 32 + s * 4);
        a2[q] = make_float4(0.4f * av.x, 0.4f * av.y, 0.4f * av.z, 0.4f * av.w);
    }

    // stage u rows i0..i0+7 into LDS (fully coalesced: 32 lanes x 16B contiguous)
    {
        const int r = tid >> 5;
        const int c = (tid & 31) * 4;
        const float* up = u_ws + ((size_t)b * KDIM + i0 + r) * EDIM;
        *(float4*)&u_lds[r * 256 + c]       = *(const float4*)(up + c);
        *(float4*)&u_lds[r * 256 + c + 128] = *(const float4*)(up + c + 128);
    }
    __syncthreads();

    // rt partial (per-lane, s-slice) — reduced later together with acc
    float rt = 0.f;
#pragma unroll
    for (int q = 0; q < 8; ++q) rt += dot4(a2[q], tld[q]);

    // ru: wave wv computes rows 2wv, 2wv+1 (fully reduced scalars)
    {
        float r0 = 0.f, r1 = 0.f;
#pragma unroll
        for (int q = 0; q < 8; ++q) {
            float4 ua = *(const float4*)&u_lds[(2 * wv) * 256 + q * 32 + s * 4];
            float4 ub = *(const float4*)&u_lds[(2 * wv + 1) * 256 + q * 32 + s * 4];
            r0 += dot4(a2[q], ua);
            r1 += dot4(a2[q], ub);
        }
        r0 += __shfl_xor(r0, 1, 64); r1 += __shfl_xor(r1, 1, 64);
        r0 += __shfl_xor(r0, 2, 64); r1 += __shfl_xor(r1, 2, 64);
        r0 += __shfl_xor(r0, 4, 64); r1 += __shfl_xor(r1, 4, 64);
        if (lane == 0) { ru_lds[2 * wv] = r0; ru_lds[2 * wv + 1] = r1; }
    }
    __syncthreads();

    // main loop: acc[i] = sum over this lane's e-slice of a2*|u_i + t_j|
    float acc[8];
#pragma unroll
    for (int i = 0; i < 8; ++i) acc[i] = 0.f;
#pragma unroll
    for (int i = 0; i < 8; ++i) {
        float a = 0.f;
#pragma unroll
        for (int q = 0; q < 8; ++q) {
            float4 u4 = *(const float4*)&u_lds[i * 256 + q * 32 + s * 4];
            float4 t4 = tld[q];
            a += a2[q].x * fabsf(u4.x + t4.x) + a2[q].y * fabsf(u4.y + t4.y)
               + a2[q].z * fabsf(u4.z + t4.z) + a2[q].w * fabsf(u4.w + t4.w);
        }
        acc[i] = a;
    }

    // reduce (acc + 1.5*rt) over s (lane bits 0..2)
#pragma unroll
    for (int i = 0; i < 8; ++i) {
        float z = acc[i] + 1.5f * rt;
        z += __shfl_xor(z, 1, 64);
        z += __shfl_xor(z, 2, 64);
        z += __shfl_xor(z, 4, 64);
        acc[i] = z;
    }
    if (s == 0) {
        const float* brow = bias + j;
        float* erow = e_ws + ((size_t)b * KDIM) * KDIM + j;
#pragma unroll
        for (int i = 0; i < 8; ++i) {
            erow[(size_t)(i0 + i) * KDIM] =
                acc[i] + 1.5f * ru_lds[i] + brow[(size_t)(i0 + i) * KDIM];
        }
    }
}

// ---------------- k_sh6: softmax + h = sigmoid(attn @ v), transposed write ----------------
// grid 1024: blk = b*256 + it*4 + wq. Block = 4 i's x 32 w's.
__global__ __launch_bounds__(256) void k_sh6(const float* __restrict__ x,
                                             const float* __restrict__ e_ws,
                                             float* __restrict__ out) {
    __shared__ float attn_lds[4][260];
    const int blk = blockIdx.x;
    const int b  = blk >> 8;
    const int it = (blk >> 2) & 63;
    const int wq = blk & 3;
    const int i0 = it * 4;
    const int w0 = wq * 32;
    const int tid  = threadIdx.x;
    const int wv   = tid >> 6;
    const int lane = tid & 63;

    // softmax of row i0+wv
    {
        float4 ev = *(const float4*)(e_ws + ((size_t)b * KDIM + i0 + wv) * KDIM + lane * 4);
        float m = fmaxf(fmaxf(ev.x, ev.y), fmaxf(ev.z, ev.w));
#pragma unroll
        for (int o = 1; o < 64; o <<= 1) m = fmaxf(m, __shfl_xor(m, o, 64));
        float4 p;
        p.x = __expf(ev.x - m); p.y = __expf(ev.y - m);
        p.z = __expf(ev.z - m); p.w = __expf(ev.w - m);
        float ssum = p.x + p.y + p.z + p.w;
#pragma unroll
        for (int o = 1; o < 64; o <<= 1) ssum += __shfl_xor(ssum, o, 64);
        const float inv = 1.0f / ssum;
        p.x *= inv; p.y *= inv; p.z *= inv; p.w *= inv;
        *(float4*)&attn_lds[wv][lane * 4] = p;
    }
    __syncthreads();

    // h-phase: wave wv -> w-oct; lane: s = lane&7 (j-slices), ww = lane>>3
    const int s  = lane & 7;
    const int ww = lane >> 3;
    const int w  = w0 + wv * 8 + ww;
    const float* xr = x + ((size_t)b * WDIM + w) * KDIM;
    float acc[4] = {0.f, 0.f, 0.f, 0.f};
#pragma unroll
    for (int q = 0; q < 8; ++q) {
        float4 x4 = *(const float4*)(xr + q * 32 + s * 4);
#pragma unroll
        for (int i = 0; i < 4; ++i) {
            float4 at = *(const float4*)&attn_lds[i][q * 32 + s * 4];
            acc[i] += dot4(at, x4);
        }
    }
#pragma unroll
    for (int i = 0; i < 4; ++i) {
        acc[i] += __shfl_xor(acc[i], 1, 64);
        acc[i] += __shfl_xor(acc[i], 2, 64);
        acc[i] += __shfl_xor(acc[i], 4, 64);
    }
    if (s == 0) {
        float4 o;
        o.x = 1.f / (1.f + __expf(-acc[0]));
        o.y = 1.f / (1.f + __expf(-acc[1]));
        o.z = 1.f / (1.f + __expf(-acc[2]));
        o.w = 1.f / (1.f + __expf(-acc[3]));
        *(float4*)(out + ((size_t)b * WDIM + w) * KDIM + i0) = o;
    }
}

extern "C" void kernel_launch(void* const* d_in, const int* in_sizes, int n_in,
                              void* d_out, int out_size, void* d_ws, size_t ws_size,
                              hipStream_t stream) {
    (void)in_sizes; (void)n_in; (void)out_size; (void)ws_size;
    const float* x     = (const float*)d_in[0];
    const float* lin_w = (const float*)d_in[1];
    const float* lin_b = (const float*)d_in[2];
    const float* a_vec = (const float*)d_in[3];
    const float* bias  = (const float*)d_in[4];
    float* out = (float*)d_out;

    float* u_ws = (float*)d_ws;                      // 262144 f
    float* t_ws = u_ws + (size_t)NB * KDIM * EDIM;   // 262144 f
    float* e_ws = t_ws + (size_t)NB * KDIM * EDIM;   // 262144 f

    k_ut6<<<512, 256, 0, stream>>>(x, lin_w, lin_b, u_ws, t_ws);
    k_e6<<<1024, 256, 0, stream>>>(a_vec, bias, u_ws, t_ws, e_ws);
    k_sh6<<<1024, 256, 0, stream>>>(x, e_ws, out);
}